// Round 9
// baseline (39838.943 us; speedup 1.0000x reference)
//
#include <hip/hip_runtime.h>
#include <cstdint>
#include <cstddef>

#define BB 128
#define EE 512
#define HH 1024
#define G4 4096
#define OO 512

__device__ __forceinline__ float sigm(float x) {
  return 1.0f / (1.0f + expf(-x));
}

// dst[c*R + r] = src[r*C + c]   (src is [R][C] row-major, fp32)
__global__ void __launch_bounds__(256)
transpose_naive(const float* __restrict__ src, float* __restrict__ dst, int R,
                int C) {
  long idx = (long)blockIdx.x * 256 + threadIdx.x;
  if (idx < (long)R * C) {
    int r = (int)(idx / C), c = (int)(idx % C);
    dst[(long)c * R + r] = src[idx];
  }
}

// zbuf[b][j] = sum_e x[b][e] * WihT[e][j] + bih[j] + bhh[j]
__global__ void __launch_bounds__(256)
z_naive(const float* __restrict__ x, const float* __restrict__ WihT,
        const float* __restrict__ bih, const float* __restrict__ bhh,
        float* __restrict__ zbuf) {
  int b = blockIdx.x;
  for (int j = threadIdx.x; j < G4; j += 256) {
    float acc = 0.f;
    for (int e = 0; e < EE; ++e) acc += x[b * EE + e] * WihT[(long)e * G4 + j];
    zbuf[(long)b * G4 + j] = acc + bih[j] + bhh[j];
  }
}

// gbuf[b][j] = zbuf[b][j] + sum_k hprev[b][k] * WhhT[k][j]
// grid 256 = 32 batch-groups (4 batches each) x 8 j-groups (512 cols each).
__global__ void __launch_bounds__(256)
gates_naive(const float* __restrict__ WhhT, const float* __restrict__ zbuf,
            const float* __restrict__ hprev, float* __restrict__ gbuf, int t) {
  __shared__ float h4[4][HH];
  int bb = blockIdx.x & 31;
  int jg = blockIdx.x >> 5;
  if (t > 0) {
    for (int idx = threadIdx.x; idx < 4 * HH; idx += 256) {
      int q = idx >> 10, k = idx & 1023;
      h4[q][k] = hprev[(long)(bb * 4 + q) * HH + k];
    }
    __syncthreads();
  }
  for (int jj = 0; jj < 2; ++jj) {
    int j = jg * 512 + jj * 256 + threadIdx.x;
    float acc[4];
#pragma unroll
    for (int q = 0; q < 4; ++q) acc[q] = zbuf[(long)(bb * 4 + q) * G4 + j];
    if (t > 0) {
      for (int k = 0; k < HH; ++k) {
        float w = WhhT[(long)k * G4 + j];
#pragma unroll
        for (int q = 0; q < 4; ++q) acc[q] += h4[q][k] * w;
      }
    }
#pragma unroll
    for (int q = 0; q < 4; ++q) gbuf[(long)(bb * 4 + q) * G4 + j] = acc[q];
  }
}

// LSTM cell elementwise. gate order i,f,g,o at columns n, H+n, 2H+n, 3H+n.
__global__ void __launch_bounds__(256)
cell_naive(const float* __restrict__ gbuf, float* __restrict__ cbuf,
           float* __restrict__ hcur, float* __restrict__ out_ns, int t, int T,
           int ns_present) {
  int b = blockIdx.x;
  for (int n = threadIdx.x; n < HH; n += 256) {
    const float* g = gbuf + (long)b * G4;
    float iv = sigm(g[n]);
    float fv = sigm(g[HH + n]);
    float gv = tanhf(g[2 * HH + n]);
    float ov = sigm(g[3 * HH + n]);
    float cold = (t == 0) ? 0.f : cbuf[(long)b * HH + n];
    float cc = fv * cold + iv * gv;
    cbuf[(long)b * HH + n] = cc;
    float hv = ov * tanhf(cc);
    hcur[(long)b * HH + n] = hv;
    if (ns_present && t == T - 1 && b == BB - 1) out_ns[n] = hv;
  }
}

// out[b][t][o] = sum_k hcur[b][k] * fcwT[k][o] + fcb[o]   (fp32 store)
__global__ void __launch_bounds__(256)
fc_naive(const float* __restrict__ hcur, const float* __restrict__ fcwT,
         const float* __restrict__ fcb, float* __restrict__ out, int t,
         int T) {
  __shared__ float hb[HH];
  int b = blockIdx.x;
  for (int i = threadIdx.x; i < HH; i += 256) hb[i] = hcur[(long)b * HH + i];
  __syncthreads();
  for (int o = threadIdx.x; o < OO; o += 256) {
    float acc = 0.f;
    for (int k = 0; k < HH; ++k) acc += hb[k] * fcwT[(long)k * OO + o];
    out[((long)b * T + t) * OO + o] = acc + fcb[o];
  }
}

extern "C" void kernel_launch(void* const* d_in, const int* in_sizes, int n_in,
                              void* d_out, int out_size, void* d_ws,
                              size_t ws_size, hipStream_t stream) {
  (void)ws_size;
  // ---- order-agnostic input identification by element count ----
  const float *x = nullptr, *Wih = nullptr, *Whh = nullptr, *fcw = nullptr;
  const float *bih = nullptr, *bhh = nullptr, *fcb = nullptr;
  for (int i = 0; i < n_in; ++i) {
    int s = in_sizes[i];
    const float* p = (const float*)d_in[i];
    if (s == BB * EE && !x) x = p;
    else if (s == 4 * HH * EE && !Wih) Wih = p;
    else if (s == 4 * HH * HH && !Whh) Whh = p;
    else if (s == OO * HH && !fcw) fcw = p;
    else if (s == 4 * HH && !bih) bih = p;
    else if (s == 4 * HH && !bhh) bhh = p;  // bias order irrelevant (summed)
    else if (s == OO && !fcb) fcb = p;
  }
  if (!x || !Wih || !Whh || !fcw || !bih || !bhh || !fcb) return;

  // ---- runtime T from out_size ----
  int T = 0, ns_present = 0;
  if (out_size >= BB * OO && (out_size - HH) % (BB * OO) == 0 &&
      (out_size - HH) / (BB * OO) >= 1) {
    T = (out_size - HH) / (BB * OO);
    ns_present = 1;
  } else if (out_size % (BB * OO) == 0) {
    T = out_size / (BB * OO);
    ns_present = 0;
  }
  if (T < 1 || T > 16384) return;

  // documented return order: out_sequence first, next_state at tail. FP32.
  float* out = (float*)d_out;
  float* out_ns = out + (long)BB * T * OO;

  // ---- ws layout (floats) ----
  float* WihT = (float*)d_ws;          // 512*4096
  float* WhhT = WihT + (long)EE * G4;  // 1024*4096
  float* fcwT = WhhT + (long)HH * G4;  // 1024*512
  float* zbuf = fcwT + (long)HH * OO;  // 128*4096
  float* gbuf = zbuf + (long)BB * G4;  // 128*4096
  float* cbuf = gbuf + (long)BB * G4;  // 128*1024
  float* hb0 = cbuf + (long)BB * HH;   // 128*1024
  float* hb1 = hb0 + (long)BB * HH;    // 128*1024

  hipLaunchKernelGGL(transpose_naive, dim3(4 * HH * EE / 256), dim3(256), 0,
                     stream, Wih, WihT, 4 * HH, EE);
  hipLaunchKernelGGL(transpose_naive, dim3(4 * HH * HH / 256), dim3(256), 0,
                     stream, Whh, WhhT, 4 * HH, HH);
  hipLaunchKernelGGL(transpose_naive, dim3(OO * HH / 256), dim3(256), 0,
                     stream, fcw, fcwT, OO, HH);
  hipLaunchKernelGGL(z_naive, dim3(BB), dim3(256), 0, stream, x, WihT, bih,
                     bhh, zbuf);

  for (int t = 0; t < T; ++t) {
    float* hcur = (t & 1) ? hb1 : hb0;
    float* hprev = (t & 1) ? hb0 : hb1;
    hipLaunchKernelGGL(gates_naive, dim3(256), dim3(256), 0, stream, WhhT,
                       zbuf, hprev, gbuf, t);
    hipLaunchKernelGGL(cell_naive, dim3(BB), dim3(256), 0, stream, gbuf, cbuf,
                       hcur, out_ns, t, T, ns_present);
    hipLaunchKernelGGL(fc_naive, dim3(BB), dim3(256), 0, stream, hcur, fcwT,
                       fcb, out, t, T);
  }
}

// Round 10
// 20853.496 us; speedup vs baseline: 1.9104x; 1.9104x over previous
//
#include <hip/hip_runtime.h>
#include <hip/hip_cooperative_groups.h>
#include <cstdint>
#include <cstddef>

namespace cg = cooperative_groups;

#define BB 128   // batch
#define EE 512   // input dim
#define HH 1024  // hidden
#define G4 4096
#define OO 512   // output dim

typedef float f32x4 __attribute__((ext_vector_type(4)));
typedef short s16x8 __attribute__((ext_vector_type(8)));
typedef __bf16 b16x8 __attribute__((ext_vector_type(8)));

// ---- mfma dispatch: tolerate either short8- or bf16x8-typed builtin ----
template <typename V>
__device__ __forceinline__ auto mfma_try(V a, V b, f32x4 c, int)
    -> decltype(__builtin_amdgcn_mfma_f32_16x16x32_bf16(a, b, c, 0, 0, 0)) {
  return __builtin_amdgcn_mfma_f32_16x16x32_bf16(a, b, c, 0, 0, 0);
}
template <typename V>
__device__ __forceinline__ f32x4 mfma_try(V a, V b, f32x4 c, long) {
  b16x8 ab = __builtin_bit_cast(b16x8, a);
  b16x8 bb = __builtin_bit_cast(b16x8, b);
  return __builtin_amdgcn_mfma_f32_16x16x32_bf16(ab, bb, c, 0, 0, 0);
}
__device__ __forceinline__ f32x4 mfma_bf16(s16x8 a, s16x8 b, f32x4 c) {
  return mfma_try(a, b, c, 0);
}

__device__ __forceinline__ float bf2f(ushort s) {
  unsigned int u = ((unsigned int)s) << 16;
  return __builtin_bit_cast(float, u);
}
__device__ __forceinline__ ushort f2bf(float f) {
  unsigned int u = __builtin_bit_cast(unsigned int, f);
  unsigned int r = (u + 0x7fffu + ((u >> 16) & 1u)) >> 16;
  return (ushort)r;
}
__device__ __forceinline__ float sigm(float x) {
  return 1.0f / (1.0f + __expf(-x));
}

// ======== fp32 -> split bf16 (hi+lo) for x, W_ih, W_hh, fc_w ============
__global__ void __launch_bounds__(256)
convert_split(const float* __restrict__ x, const float* __restrict__ Wih,
              const float* __restrict__ Whh, const float* __restrict__ fcw,
              ushort* __restrict__ xh, ushort* __restrict__ xl,
              ushort* __restrict__ Wihh, ushort* __restrict__ Wihl,
              ushort* __restrict__ Whhh, ushort* __restrict__ Whhl,
              ushort* __restrict__ fcwh, ushort* __restrict__ fcwl) {
  const long n0 = (long)BB * EE;
  const long n1 = n0 + (long)G4 * EE;
  const long n2 = n1 + (long)G4 * HH;
  long i = ((long)blockIdx.x * 256 + threadIdx.x) * 4;
  const float* src;
  ushort *dh, *dl;
  long off;
  if (i < n0) {
    src = x; dh = xh; dl = xl; off = i;
  } else if (i < n1) {
    src = Wih; dh = Wihh; dl = Wihl; off = i - n0;
  } else if (i < n2) {
    src = Whh; dh = Whhh; dl = Whhl; off = i - n1;
  } else {
    src = fcw; dh = fcwh; dl = fcwl; off = i - n2;
  }
  float4 v = *(const float4*)&src[off];
  ushort4 h;
  h.x = f2bf(v.x); h.y = f2bf(v.y); h.z = f2bf(v.z); h.w = f2bf(v.w);
  *(ushort4*)&dh[off] = h;
  ushort4 l;
  l.x = f2bf(v.x - bf2f(h.x));
  l.y = f2bf(v.y - bf2f(h.y));
  l.z = f2bf(v.z - bf2f(h.z));
  l.w = f2bf(v.w - bf2f(h.w));
  *(ushort4*)&dl[off] = l;
}

// =====================================================================
// Persistent cooperative kernel: split-precision LSTM recurrence + FC.
// Recurrence: 256 blocks = 2 m-tiles (64 rows) x 128 h-slices (8 cols);
// block owns gate cols g*1024+hbase+c -> cell update block-local; one
// grid.sync per step. GEMMs: 3-term split-bf16 MFMA (~fp32 accuracy).
// FC: 256 blocks = 8 m-tiles x 32 o-tiles, waves split K, LDS reduce.
// All outputs fp32 (out_sequence head, next_state tail).
// =====================================================================
__global__ void __launch_bounds__(256)
lstm_fused(const ushort* __restrict__ xh, const ushort* __restrict__ xl,
           const ushort* __restrict__ Wihh, const ushort* __restrict__ Wihl,
           const ushort* __restrict__ Whhh, const ushort* __restrict__ Whhl,
           const float* __restrict__ bih, const float* __restrict__ bhh,
           const ushort* __restrict__ fcwh, const ushort* __restrict__ fcwl,
           const float* __restrict__ fcb, ushort* __restrict__ hbh,
           ushort* __restrict__ hbl, float* __restrict__ out,
           float* __restrict__ out_ns, int T) {
  __shared__ alignas(16) ushort Ah[64][72];
  __shared__ alignas(16) ushort Al[64][72];
  __shared__ alignas(16) ushort Bh[32][72];
  __shared__ alignas(16) ushort Bl[32][72];
  __shared__ alignas(16) float zs[64][32];
  __shared__ alignas(16) float gs[64][32];
  __shared__ alignas(16) float cs[64][8];
  __shared__ alignas(16) float fcred[4][16][16];

  const int tid = threadIdx.x;
  const int bid = blockIdx.x;
  const int m0 = (bid >> 7) * 64;
  const int hbase = (bid & 127) * 8;
  const int lane = tid & 63;
  const int wave = tid >> 6;
  const int wm = wave & 1, wn = wave >> 1;
  const int fr_row = lane & 15, fr_k = (lane >> 4) * 8;
  const int m0f = (bid >> 5) * 16;  // fc m-tile
  const int o0 = (bid & 31) * 16;   // fc o-tile
  const f32x4 fz = {0.f, 0.f, 0.f, 0.f};

  // ---------------- phase 0: z = x @ W_ih^T + (b_ih+b_hh) --------------
  {
    f32x4 a0 = fz, a1 = fz;
    for (int kt = 0; kt < EE / 64; ++kt) {
      for (int i = 0; i < 2; ++i) {
        int idx = tid + i * 256;
        int r = idx >> 3, c8 = (idx & 7) * 8;
        int go = (m0 + r) * EE + kt * 64 + c8;
        *(uint4*)&Ah[r][c8] = *(const uint4*)&xh[go];
        *(uint4*)&Al[r][c8] = *(const uint4*)&xl[go];
      }
      {
        int r = tid >> 3, c8 = (tid & 7) * 8;
        int wrow = (r >> 3) * HH + hbase + (r & 7);
        int go = wrow * EE + kt * 64 + c8;
        *(uint4*)&Bh[r][c8] = *(const uint4*)&Wihh[go];
        *(uint4*)&Bl[r][c8] = *(const uint4*)&Wihl[go];
      }
      __syncthreads();
      for (int kc = 0; kc < 2; ++kc) {
        int ko = kc * 32 + fr_k;
        s16x8 bh = *(const s16x8*)&Bh[wn * 16 + fr_row][ko];
        s16x8 bl = *(const s16x8*)&Bl[wn * 16 + fr_row][ko];
        s16x8 f0h = *(const s16x8*)&Ah[wm * 32 + fr_row][ko];
        s16x8 f0l = *(const s16x8*)&Al[wm * 32 + fr_row][ko];
        s16x8 f1h = *(const s16x8*)&Ah[wm * 32 + 16 + fr_row][ko];
        s16x8 f1l = *(const s16x8*)&Al[wm * 32 + 16 + fr_row][ko];
        a0 = mfma_bf16(f0h, bh, a0);
        a0 = mfma_bf16(f0l, bh, a0);
        a0 = mfma_bf16(f0h, bl, a0);
        a1 = mfma_bf16(f1h, bh, a1);
        a1 = mfma_bf16(f1l, bh, a1);
        a1 = mfma_bf16(f1h, bl, a1);
      }
      __syncthreads();
    }
    int jcol = wn * 16 + fr_row;
    int gc = (jcol >> 3) * HH + hbase + (jcol & 7);
    float bias = bih[gc] + bhh[gc];
    int rbase = wm * 32 + (lane >> 4) * 4;
#pragma unroll
    for (int r = 0; r < 4; ++r) {
      zs[rbase + r][jcol] = a0[r] + bias;
      zs[rbase + 16 + r][jcol] = a1[r] + bias;
    }
    int m = tid >> 2, cp = (tid & 3) * 2;
    cs[m][cp] = 0.0f;
    cs[m][cp + 1] = 0.0f;
    __syncthreads();
  }

  cg::grid_group grid = cg::this_grid();

  // ---------------- step loop ------------------------------------------
  for (int t = 0; t < T; ++t) {
    f32x4 g0 = fz, g1 = fz;
    if (t > 0) {
      const ushort* hph = hbh + ((t - 1) & 1) * (BB * HH);
      const ushort* hpl = hbl + ((t - 1) & 1) * (BB * HH);
      for (int kt = 0; kt < HH / 64; ++kt) {
        for (int i = 0; i < 2; ++i) {
          int idx = tid + i * 256;
          int r = idx >> 3, c8 = (idx & 7) * 8;
          int go = (m0 + r) * HH + kt * 64 + c8;
          *(uint4*)&Ah[r][c8] = *(const uint4*)&hph[go];
          *(uint4*)&Al[r][c8] = *(const uint4*)&hpl[go];
        }
        {
          int r = tid >> 3, c8 = (tid & 7) * 8;
          int wrow = (r >> 3) * HH + hbase + (r & 7);
          int go = wrow * HH + kt * 64 + c8;
          *(uint4*)&Bh[r][c8] = *(const uint4*)&Whhh[go];
          *(uint4*)&Bl[r][c8] = *(const uint4*)&Whhl[go];
        }
        __syncthreads();
        for (int kc = 0; kc < 2; ++kc) {
          int ko = kc * 32 + fr_k;
          s16x8 bh = *(const s16x8*)&Bh[wn * 16 + fr_row][ko];
          s16x8 bl = *(const s16x8*)&Bl[wn * 16 + fr_row][ko];
          s16x8 f0h = *(const s16x8*)&Ah[wm * 32 + fr_row][ko];
          s16x8 f0l = *(const s16x8*)&Al[wm * 32 + fr_row][ko];
          s16x8 f1h = *(const s16x8*)&Ah[wm * 32 + 16 + fr_row][ko];
          s16x8 f1l = *(const s16x8*)&Al[wm * 32 + 16 + fr_row][ko];
          g0 = mfma_bf16(f0h, bh, g0);
          g0 = mfma_bf16(f0l, bh, g0);
          g0 = mfma_bf16(f0h, bl, g0);
          g1 = mfma_bf16(f1h, bh, g1);
          g1 = mfma_bf16(f1l, bh, g1);
          g1 = mfma_bf16(f1h, bl, g1);
        }
        __syncthreads();
      }
    }
    // scatter gate accumulators to LDS
    {
      int jcol = wn * 16 + fr_row;
      int rbase = wm * 32 + (lane >> 4) * 4;
#pragma unroll
      for (int r = 0; r < 4; ++r) {
        gs[rbase + r][jcol] = g0[r];
        gs[rbase + 16 + r][jcol] = g1[r];
      }
    }
    __syncthreads();
    // elementwise LSTM cell (fp32); h stored split bf16
    {
      int m = tid >> 2, cp = (tid & 3) * 2;
      ushort hhv[2], hlv[2];
      float hvf[2];
#pragma unroll
      for (int q = 0; q < 2; ++q) {
        int c = cp + q;
        float iv = sigm(zs[m][c] + gs[m][c]);
        float fv = sigm(zs[m][8 + c] + gs[m][8 + c]);
        float gv = tanhf(zs[m][16 + c] + gs[m][16 + c]);
        float ov = sigm(zs[m][24 + c] + gs[m][24 + c]);
        float cc = fv * cs[m][c] + iv * gv;
        cs[m][c] = cc;
        float hv = ov * tanhf(cc);
        hvf[q] = hv;
        hhv[q] = f2bf(hv);
        hlv[q] = f2bf(hv - bf2f(hhv[q]));
      }
      unsigned int ph = ((unsigned int)hhv[1] << 16) | (unsigned int)hhv[0];
      unsigned int pl = ((unsigned int)hlv[1] << 16) | (unsigned int)hlv[0];
      int gb = m0 + m;
      size_t go = (size_t)(t & 1) * (BB * HH) + gb * HH + hbase + cp;
      *(unsigned int*)&hbh[go] = ph;
      *(unsigned int*)&hbl[go] = pl;
      if (t == T - 1 && gb == BB - 1) {
        out_ns[hbase + cp] = hvf[0];
        out_ns[hbase + cp + 1] = hvf[1];
      }
    }
    __threadfence();
    grid.sync();

    // ------------- fused FC for this step: out[:, t, :] ----------------
    {
      const ushort* hch = hbh + (t & 1) * (BB * HH);
      const ushort* hcl = hbl + (t & 1) * (BB * HH);
      f32x4 acc = fz;
      const int kbase = wave * 256;
      for (int k8 = 0; k8 < 8; ++k8) {
        int kk = kbase + k8 * 32 + fr_k;
        s16x8 afh = *(const s16x8*)&hch[(m0f + fr_row) * HH + kk];
        s16x8 afl = *(const s16x8*)&hcl[(m0f + fr_row) * HH + kk];
        s16x8 bh = *(const s16x8*)&fcwh[(o0 + fr_row) * HH + kk];
        s16x8 bl = *(const s16x8*)&fcwl[(o0 + fr_row) * HH + kk];
        acc = mfma_bf16(afh, bh, acc);
        acc = mfma_bf16(afl, bh, acc);
        acc = mfma_bf16(afh, bl, acc);
      }
      int rrow = (lane >> 4) * 4;
#pragma unroll
      for (int r = 0; r < 4; ++r) fcred[wave][rrow + r][fr_row] = acc[r];
      __syncthreads();
      {
        int row = tid >> 4, col = tid & 15;
        float s = fcred[0][row][col] + fcred[1][row][col] +
                  fcred[2][row][col] + fcred[3][row][col] + fcb[o0 + col];
        out[((size_t)(m0f + row) * T + t) * OO + o0 + col] = s;
      }
    }
  }
}

extern "C" void kernel_launch(void* const* d_in, const int* in_sizes, int n_in,
                              void* d_out, int out_size, void* d_ws,
                              size_t ws_size, hipStream_t stream) {
  (void)ws_size;
  // ---- order-agnostic input identification by element count ----
  const float *x = nullptr, *Wih = nullptr, *Whh = nullptr, *fcw = nullptr;
  const float *bih = nullptr, *bhh = nullptr, *fcb = nullptr;
  for (int i = 0; i < n_in; ++i) {
    int s = in_sizes[i];
    const float* p = (const float*)d_in[i];
    if (s == BB * EE && !x) x = p;
    else if (s == G4 * EE && !Wih) Wih = p;
    else if (s == G4 * HH && !Whh) Whh = p;
    else if (s == OO * HH && !fcw) fcw = p;
    else if (s == G4 && !bih) bih = p;
    else if (s == G4 && !bhh) bhh = p;  // bias order irrelevant (summed)
    else if (s == OO && !fcb) fcb = p;
  }
  if (!x || !Wih || !Whh || !fcw || !bih || !bhh || !fcb) return;

  // ---- runtime T from out_size ----
  int T = 0;
  if (out_size >= BB * OO && (out_size - HH) % (BB * OO) == 0 &&
      (out_size - HH) / (BB * OO) >= 1) {
    T = (out_size - HH) / (BB * OO);
  } else if (out_size % (BB * OO) == 0) {
    T = out_size / (BB * OO);
  }
  if (T < 1 || T > 16384) return;

  float* out = (float*)d_out;
  float* out_ns = out + (size_t)BB * T * OO;

  // ---- ws layout (ushort elements) ----
  ushort* xh = (ushort*)d_ws;
  ushort* xl = xh + (size_t)BB * EE;
  ushort* Wihh = xl + (size_t)BB * EE;
  ushort* Wihl = Wihh + (size_t)G4 * EE;
  ushort* Whhh = Wihl + (size_t)G4 * EE;
  ushort* Whhl = Whhh + (size_t)G4 * HH;
  ushort* fcwh = Whhl + (size_t)G4 * HH;
  ushort* fcwl = fcwh + (size_t)OO * HH;
  ushort* hbh = fcwl + (size_t)OO * HH;
  ushort* hbl = hbh + (size_t)2 * BB * HH;

  {
    long total = (long)BB * EE + (long)G4 * EE + (long)G4 * HH + (long)OO * HH;
    int cblocks = (int)(total / 4 / 256);  // 6720, exact
    hipLaunchKernelGGL(convert_split, dim3(cblocks), dim3(256), 0, stream, x,
                       Wih, Whh, fcw, xh, xl, Wihh, Wihl, Whhh, Whhl, fcwh,
                       fcwl);
  }
  void* args[] = {(void*)&xh,   (void*)&xl,   (void*)&Wihh, (void*)&Wihl,
                  (void*)&Whhh, (void*)&Whhl, (void*)&bih,  (void*)&bhh,
                  (void*)&fcwh, (void*)&fcwl, (void*)&fcb,  (void*)&hbh,
                  (void*)&hbl,  (void*)&out,  (void*)&out_ns, (void*)&T};
  hipLaunchCooperativeKernel((void*)lstm_fused, dim3(256), dim3(256), args, 0,
                             stream);
}

// Round 11
// 5451.392 us; speedup vs baseline: 7.3080x; 3.8254x over previous
//
#include <hip/hip_runtime.h>
#include <cstdint>
#include <cstddef>

#define BB 128   // batch
#define EE 512   // input dim
#define HH 1024  // hidden
#define G4 4096
#define OO 512   // output dim

typedef float f32x4 __attribute__((ext_vector_type(4)));
typedef short s16x8 __attribute__((ext_vector_type(8)));
typedef __bf16 b16x8 __attribute__((ext_vector_type(8)));

// ---- mfma dispatch: tolerate either short8- or bf16x8-typed builtin ----
template <typename V>
__device__ __forceinline__ auto mfma_try(V a, V b, f32x4 c, int)
    -> decltype(__builtin_amdgcn_mfma_f32_16x16x32_bf16(a, b, c, 0, 0, 0)) {
  return __builtin_amdgcn_mfma_f32_16x16x32_bf16(a, b, c, 0, 0, 0);
}
template <typename V>
__device__ __forceinline__ f32x4 mfma_try(V a, V b, f32x4 c, long) {
  b16x8 ab = __builtin_bit_cast(b16x8, a);
  b16x8 bb = __builtin_bit_cast(b16x8, b);
  return __builtin_amdgcn_mfma_f32_16x16x32_bf16(ab, bb, c, 0, 0, 0);
}
__device__ __forceinline__ f32x4 mfma_bf16(s16x8 a, s16x8 b, f32x4 c) {
  return mfma_try(a, b, c, 0);
}

__device__ __forceinline__ float bf2f(ushort s) {
  unsigned int u = ((unsigned int)s) << 16;
  return __builtin_bit_cast(float, u);
}
__device__ __forceinline__ ushort f2bf(float f) {
  unsigned int u = __builtin_bit_cast(unsigned int, f);
  unsigned int r = (u + 0x7fffu + ((u >> 16) & 1u)) >> 16;
  return (ushort)r;
}
__device__ __forceinline__ float sigm(float x) {
  return 1.0f / (1.0f + __expf(-x));
}

// ======== fp32 -> split bf16 (hi+lo) for x, W_ih, W_hh, fc_w ============
__global__ void __launch_bounds__(256)
convert_split(const float* __restrict__ x, const float* __restrict__ Wih,
              const float* __restrict__ Whh, const float* __restrict__ fcw,
              ushort* __restrict__ xh, ushort* __restrict__ xl,
              ushort* __restrict__ Wihh, ushort* __restrict__ Wihl,
              ushort* __restrict__ Whhh, ushort* __restrict__ Whhl,
              ushort* __restrict__ fcwh, ushort* __restrict__ fcwl) {
  const long n0 = (long)BB * EE;
  const long n1 = n0 + (long)G4 * EE;
  const long n2 = n1 + (long)G4 * HH;
  long i = ((long)blockIdx.x * 256 + threadIdx.x) * 4;
  const float* src;
  ushort *dh, *dl;
  long off;
  if (i < n0) {
    src = x; dh = xh; dl = xl; off = i;
  } else if (i < n1) {
    src = Wih; dh = Wihh; dl = Wihl; off = i - n0;
  } else if (i < n2) {
    src = Whh; dh = Whhh; dl = Whhl; off = i - n1;
  } else {
    src = fcw; dh = fcwh; dl = fcwl; off = i - n2;
  }
  float4 v = *(const float4*)&src[off];
  ushort4 h;
  h.x = f2bf(v.x); h.y = f2bf(v.y); h.z = f2bf(v.z); h.w = f2bf(v.w);
  *(ushort4*)&dh[off] = h;
  ushort4 l;
  l.x = f2bf(v.x - bf2f(h.x));
  l.y = f2bf(v.y - bf2f(h.y));
  l.z = f2bf(v.z - bf2f(h.z));
  l.w = f2bf(v.w - bf2f(h.w));
  *(ushort4*)&dl[off] = l;
}

// ========== z = x @ W_ih^T + (b_ih+b_hh) -> zbuf fp32 [B][4H] ===========
// 256 blocks = 2 m-tiles (64 rows) x 128 h-slices (32 gate cols each).
__global__ void __launch_bounds__(256)
z_split(const ushort* __restrict__ xh, const ushort* __restrict__ xl,
        const ushort* __restrict__ Wihh, const ushort* __restrict__ Wihl,
        const float* __restrict__ bih, const float* __restrict__ bhh,
        float* __restrict__ zbuf) {
  __shared__ alignas(16) ushort Ah[64][72];
  __shared__ alignas(16) ushort Al[64][72];
  __shared__ alignas(16) ushort Bh[32][72];
  __shared__ alignas(16) ushort Bl[32][72];
  const int tid = threadIdx.x, bid = blockIdx.x;
  const int m0 = (bid >> 7) * 64;
  const int hbase = (bid & 127) * 8;
  const int lane = tid & 63, wave = tid >> 6;
  const int wm = wave & 1, wn = wave >> 1;
  const int fr_row = lane & 15, fr_k = (lane >> 4) * 8;
  const f32x4 fz = {0.f, 0.f, 0.f, 0.f};

  f32x4 a0 = fz, a1 = fz;
  for (int kt = 0; kt < EE / 64; ++kt) {
    for (int i = 0; i < 2; ++i) {
      int idx = tid + i * 256;
      int r = idx >> 3, c8 = (idx & 7) * 8;
      int go = (m0 + r) * EE + kt * 64 + c8;
      *(uint4*)&Ah[r][c8] = *(const uint4*)&xh[go];
      *(uint4*)&Al[r][c8] = *(const uint4*)&xl[go];
    }
    {
      int r = tid >> 3, c8 = (tid & 7) * 8;
      int wrow = (r >> 3) * HH + hbase + (r & 7);
      int go = wrow * EE + kt * 64 + c8;
      *(uint4*)&Bh[r][c8] = *(const uint4*)&Wihh[go];
      *(uint4*)&Bl[r][c8] = *(const uint4*)&Wihl[go];
    }
    __syncthreads();
    for (int kc = 0; kc < 2; ++kc) {
      int ko = kc * 32 + fr_k;
      s16x8 bh = *(const s16x8*)&Bh[wn * 16 + fr_row][ko];
      s16x8 bl = *(const s16x8*)&Bl[wn * 16 + fr_row][ko];
      s16x8 f0h = *(const s16x8*)&Ah[wm * 32 + fr_row][ko];
      s16x8 f0l = *(const s16x8*)&Al[wm * 32 + fr_row][ko];
      s16x8 f1h = *(const s16x8*)&Ah[wm * 32 + 16 + fr_row][ko];
      s16x8 f1l = *(const s16x8*)&Al[wm * 32 + 16 + fr_row][ko];
      a0 = mfma_bf16(f0h, bh, a0);
      a0 = mfma_bf16(f0l, bh, a0);
      a0 = mfma_bf16(f0h, bl, a0);
      a1 = mfma_bf16(f1h, bh, a1);
      a1 = mfma_bf16(f1l, bh, a1);
      a1 = mfma_bf16(f1h, bl, a1);
    }
    __syncthreads();
  }
  int jcol = wn * 16 + fr_row;
  int gc = (jcol >> 3) * HH + hbase + (jcol & 7);
  float bias = bih[gc] + bhh[gc];
  int rbase = wm * 32 + (lane >> 4) * 4;
#pragma unroll
  for (int r = 0; r < 4; ++r) {
    zbuf[(size_t)(m0 + rbase + r) * G4 + gc] = a0[r] + bias;
    zbuf[(size_t)(m0 + rbase + 16 + r) * G4 + gc] = a1[r] + bias;
  }
}

// =====================================================================
// One step, kernel-boundary synced, FC fused one step delayed.
// If t < T: recurrence h_{t-1} -> h_t (256 blocks = 2 m-tiles x 128
//           h-slices of 8 cols; block owns its gate cols -> cell local).
// If t > 0: FC out[:, t-1, :] from h_{t-1} (8 m-tiles x 32 o-tiles,
//           waves split K, LDS reduce). Both only read h_{t-1}.
// =====================================================================
__global__ void __launch_bounds__(256)
step_kernel(const ushort* __restrict__ Whhh, const ushort* __restrict__ Whhl,
            const float* __restrict__ zbuf, float* __restrict__ cbuf,
            ushort* __restrict__ hbh, ushort* __restrict__ hbl,
            const ushort* __restrict__ fcwh, const ushort* __restrict__ fcwl,
            const float* __restrict__ fcb, float* __restrict__ out,
            float* __restrict__ out_ns, int t, int T) {
  __shared__ alignas(16) ushort Ah[64][72];
  __shared__ alignas(16) ushort Al[64][72];
  __shared__ alignas(16) ushort Bh[32][72];
  __shared__ alignas(16) ushort Bl[32][72];
  __shared__ alignas(16) float gs[64][32];
  __shared__ alignas(16) float fcred[4][16][16];

  const int tid = threadIdx.x;
  const int bid = blockIdx.x;
  const int m0 = (bid >> 7) * 64;
  const int hbase = (bid & 127) * 8;
  const int lane = tid & 63;
  const int wave = tid >> 6;
  const int wm = wave & 1, wn = wave >> 1;
  const int fr_row = lane & 15, fr_k = (lane >> 4) * 8;
  const f32x4 fz = {0.f, 0.f, 0.f, 0.f};

  if (t < T) {
    f32x4 g0 = fz, g1 = fz;
    if (t > 0) {
      const ushort* hph = hbh + ((t - 1) & 1) * (BB * HH);
      const ushort* hpl = hbl + ((t - 1) & 1) * (BB * HH);
      for (int kt = 0; kt < HH / 64; ++kt) {
        for (int i = 0; i < 2; ++i) {
          int idx = tid + i * 256;
          int r = idx >> 3, c8 = (idx & 7) * 8;
          int go = (m0 + r) * HH + kt * 64 + c8;
          *(uint4*)&Ah[r][c8] = *(const uint4*)&hph[go];
          *(uint4*)&Al[r][c8] = *(const uint4*)&hpl[go];
        }
        {
          int r = tid >> 3, c8 = (tid & 7) * 8;
          int wrow = (r >> 3) * HH + hbase + (r & 7);
          int go = wrow * HH + kt * 64 + c8;
          *(uint4*)&Bh[r][c8] = *(const uint4*)&Whhh[go];
          *(uint4*)&Bl[r][c8] = *(const uint4*)&Whhl[go];
        }
        __syncthreads();
        for (int kc = 0; kc < 2; ++kc) {
          int ko = kc * 32 + fr_k;
          s16x8 bh = *(const s16x8*)&Bh[wn * 16 + fr_row][ko];
          s16x8 bl = *(const s16x8*)&Bl[wn * 16 + fr_row][ko];
          s16x8 f0h = *(const s16x8*)&Ah[wm * 32 + fr_row][ko];
          s16x8 f0l = *(const s16x8*)&Al[wm * 32 + fr_row][ko];
          s16x8 f1h = *(const s16x8*)&Ah[wm * 32 + 16 + fr_row][ko];
          s16x8 f1l = *(const s16x8*)&Al[wm * 32 + 16 + fr_row][ko];
          g0 = mfma_bf16(f0h, bh, g0);
          g0 = mfma_bf16(f0l, bh, g0);
          g0 = mfma_bf16(f0h, bl, g0);
          g1 = mfma_bf16(f1h, bh, g1);
          g1 = mfma_bf16(f1l, bh, g1);
          g1 = mfma_bf16(f1h, bl, g1);
        }
        __syncthreads();
      }
    }
    // scatter gate accumulators to LDS
    {
      int jcol = wn * 16 + fr_row;
      int rbase = wm * 32 + (lane >> 4) * 4;
#pragma unroll
      for (int r = 0; r < 4; ++r) {
        gs[rbase + r][jcol] = g0[r];
        gs[rbase + 16 + r][jcol] = g1[r];
      }
    }
    __syncthreads();
    // elementwise LSTM cell (fp32); h stored split bf16, c fp32 global
    {
      int m = tid >> 2, cp = (tid & 3) * 2;
      int gb = m0 + m;
      const float* zb = zbuf + (size_t)gb * G4;
      float2 cv;
      if (t == 0) {
        cv.x = 0.f; cv.y = 0.f;
      } else {
        cv = *(const float2*)&cbuf[gb * HH + hbase + cp];
      }
      ushort hhv[2], hlv[2];
      float hvf[2], cn[2];
#pragma unroll
      for (int q = 0; q < 2; ++q) {
        int c = cp + q;
        int hc = hbase + c;
        float iv = sigm(zb[hc] + gs[m][c]);
        float fv = sigm(zb[HH + hc] + gs[m][8 + c]);
        float gv = tanhf(zb[2 * HH + hc] + gs[m][16 + c]);
        float ov = sigm(zb[3 * HH + hc] + gs[m][24 + c]);
        float cc = fv * (q ? cv.y : cv.x) + iv * gv;
        cn[q] = cc;
        float hv = ov * tanhf(cc);
        hvf[q] = hv;
        hhv[q] = f2bf(hv);
        hlv[q] = f2bf(hv - bf2f(hhv[q]));
      }
      float2 cw; cw.x = cn[0]; cw.y = cn[1];
      *(float2*)&cbuf[gb * HH + hbase + cp] = cw;
      unsigned int ph = ((unsigned int)hhv[1] << 16) | (unsigned int)hhv[0];
      unsigned int pl = ((unsigned int)hlv[1] << 16) | (unsigned int)hlv[0];
      size_t go = (size_t)(t & 1) * (BB * HH) + gb * HH + hbase + cp;
      *(unsigned int*)&hbh[go] = ph;
      *(unsigned int*)&hbl[go] = pl;
      if (t == T - 1 && gb == BB - 1) {
        out_ns[hbase + cp] = hvf[0];
        out_ns[hbase + cp + 1] = hvf[1];
      }
    }
  }

  // ------------- delayed FC: out[:, t-1, :] from h_{t-1} ----------------
  if (t > 0) {
    const int m0f = (bid >> 5) * 16;
    const int o0 = (bid & 31) * 16;
    const ushort* hch = hbh + ((t - 1) & 1) * (BB * HH);
    const ushort* hcl = hbl + ((t - 1) & 1) * (BB * HH);
    f32x4 acc = fz;
    const int kbase = wave * 256;
    for (int k8 = 0; k8 < 8; ++k8) {
      int kk = kbase + k8 * 32 + fr_k;
      s16x8 afh = *(const s16x8*)&hch[(m0f + fr_row) * HH + kk];
      s16x8 afl = *(const s16x8*)&hcl[(m0f + fr_row) * HH + kk];
      s16x8 bh = *(const s16x8*)&fcwh[(o0 + fr_row) * HH + kk];
      s16x8 bl = *(const s16x8*)&fcwl[(o0 + fr_row) * HH + kk];
      acc = mfma_bf16(afh, bh, acc);
      acc = mfma_bf16(afl, bh, acc);
      acc = mfma_bf16(afh, bl, acc);
    }
    int rrow = (lane >> 4) * 4;
#pragma unroll
    for (int r = 0; r < 4; ++r) fcred[wave][rrow + r][fr_row] = acc[r];
    __syncthreads();
    {
      int row = tid >> 4, col = tid & 15;
      float s = fcred[0][row][col] + fcred[1][row][col] + fcred[2][row][col] +
                fcred[3][row][col] + fcb[o0 + col];
      out[((size_t)(m0f + row) * T + (t - 1)) * OO + o0 + col] = s;
    }
  }
}

extern "C" void kernel_launch(void* const* d_in, const int* in_sizes, int n_in,
                              void* d_out, int out_size, void* d_ws,
                              size_t ws_size, hipStream_t stream) {
  (void)ws_size;
  // ---- order-agnostic input identification by element count ----
  const float *x = nullptr, *Wih = nullptr, *Whh = nullptr, *fcw = nullptr;
  const float *bih = nullptr, *bhh = nullptr, *fcb = nullptr;
  for (int i = 0; i < n_in; ++i) {
    int s = in_sizes[i];
    const float* p = (const float*)d_in[i];
    if (s == BB * EE && !x) x = p;
    else if (s == G4 * EE && !Wih) Wih = p;
    else if (s == G4 * HH && !Whh) Whh = p;
    else if (s == OO * HH && !fcw) fcw = p;
    else if (s == G4 && !bih) bih = p;
    else if (s == G4 && !bhh) bhh = p;  // bias order irrelevant (summed)
    else if (s == OO && !fcb) fcb = p;
  }
  if (!x || !Wih || !Whh || !fcw || !bih || !bhh || !fcb) return;

  // ---- runtime T from out_size ----
  int T = 0;
  if (out_size >= BB * OO && (out_size - HH) % (BB * OO) == 0 &&
      (out_size - HH) / (BB * OO) >= 1) {
    T = (out_size - HH) / (BB * OO);
  } else if (out_size % (BB * OO) == 0) {
    T = out_size / (BB * OO);
  }
  if (T < 1 || T > 16384) return;

  float* out = (float*)d_out;
  float* out_ns = out + (size_t)BB * T * OO;

  // ---- ws layout ----
  ushort* xh = (ushort*)d_ws;
  ushort* xl = xh + (size_t)BB * EE;
  ushort* Wihh = xl + (size_t)BB * EE;
  ushort* Wihl = Wihh + (size_t)G4 * EE;
  ushort* Whhh = Wihl + (size_t)G4 * EE;
  ushort* Whhl = Whhh + (size_t)G4 * HH;
  ushort* fcwh = Whhl + (size_t)G4 * HH;
  ushort* fcwl = fcwh + (size_t)OO * HH;
  ushort* hbh = fcwl + (size_t)OO * HH;
  ushort* hbl = hbh + (size_t)2 * BB * HH;
  float* zbuf = (float*)(hbl + (size_t)2 * BB * HH);  // 128*4096 f32
  float* cbuf = zbuf + (size_t)BB * G4;               // 128*1024 f32

  {
    long total = (long)BB * EE + (long)G4 * EE + (long)G4 * HH + (long)OO * HH;
    int cblocks = (int)(total / 4 / 256);  // exact
    hipLaunchKernelGGL(convert_split, dim3(cblocks), dim3(256), 0, stream, x,
                       Wih, Whh, fcw, xh, xl, Wihh, Wihl, Whhh, Whhl, fcwh,
                       fcwl);
  }
  hipLaunchKernelGGL(z_split, dim3(256), dim3(256), 0, stream, xh, xl, Wihh,
                     Wihl, bih, bhh, zbuf);

  for (int t = 0; t <= T; ++t) {
    hipLaunchKernelGGL(step_kernel, dim3(256), dim3(256), 0, stream, Whhh,
                       Whhl, zbuf, cbuf, hbh, hbl, fcwh, fcwl, fcb, out,
                       out_ns, t, T);
  }
}

// Round 12
// 4613.045 us; speedup vs baseline: 8.6361x; 1.1817x over previous
//
#include <hip/hip_runtime.h>
#include <cstdint>
#include <cstddef>

#define BB 128   // batch
#define EE 512   // input dim
#define HH 1024  // hidden
#define G4 4096
#define OO 512   // output dim

typedef float f32x4 __attribute__((ext_vector_type(4)));
typedef short s16x8 __attribute__((ext_vector_type(8)));
typedef __bf16 b16x8 __attribute__((ext_vector_type(8)));

// ---- mfma dispatch: tolerate either short8- or bf16x8-typed builtin ----
template <typename V>
__device__ __forceinline__ auto mfma_try(V a, V b, f32x4 c, int)
    -> decltype(__builtin_amdgcn_mfma_f32_16x16x32_bf16(a, b, c, 0, 0, 0)) {
  return __builtin_amdgcn_mfma_f32_16x16x32_bf16(a, b, c, 0, 0, 0);
}
template <typename V>
__device__ __forceinline__ f32x4 mfma_try(V a, V b, f32x4 c, long) {
  b16x8 ab = __builtin_bit_cast(b16x8, a);
  b16x8 bb = __builtin_bit_cast(b16x8, b);
  return __builtin_amdgcn_mfma_f32_16x16x32_bf16(ab, bb, c, 0, 0, 0);
}
__device__ __forceinline__ f32x4 mfma_bf16(s16x8 a, s16x8 b, f32x4 c) {
  return mfma_try(a, b, c, 0);
}

__device__ __forceinline__ float bf2f(ushort s) {
  unsigned int u = ((unsigned int)s) << 16;
  return __builtin_bit_cast(float, u);
}
__device__ __forceinline__ ushort f2bf(float f) {
  unsigned int u = __builtin_bit_cast(unsigned int, f);
  unsigned int r = (u + 0x7fffu + ((u >> 16) & 1u)) >> 16;
  return (ushort)r;
}
__device__ __forceinline__ float sigm(float x) {
  return 1.0f / (1.0f + __expf(-x));
}

// ======== fp32 -> split bf16 (hi+lo) for x, W_ih, W_hh, fc_w ============
__global__ void __launch_bounds__(256)
convert_split(const float* __restrict__ x, const float* __restrict__ Wih,
              const float* __restrict__ Whh, const float* __restrict__ fcw,
              ushort* __restrict__ xh, ushort* __restrict__ xl,
              ushort* __restrict__ Wihh, ushort* __restrict__ Wihl,
              ushort* __restrict__ Whhh, ushort* __restrict__ Whhl,
              ushort* __restrict__ fcwh, ushort* __restrict__ fcwl) {
  const long n0 = (long)BB * EE;
  const long n1 = n0 + (long)G4 * EE;
  const long n2 = n1 + (long)G4 * HH;
  long i = ((long)blockIdx.x * 256 + threadIdx.x) * 4;
  const float* src;
  ushort *dh, *dl;
  long off;
  if (i < n0) {
    src = x; dh = xh; dl = xl; off = i;
  } else if (i < n1) {
    src = Wih; dh = Wihh; dl = Wihl; off = i - n0;
  } else if (i < n2) {
    src = Whh; dh = Whhh; dl = Whhl; off = i - n1;
  } else {
    src = fcw; dh = fcwh; dl = fcwl; off = i - n2;
  }
  float4 v = *(const float4*)&src[off];
  ushort4 h;
  h.x = f2bf(v.x); h.y = f2bf(v.y); h.z = f2bf(v.z); h.w = f2bf(v.w);
  *(ushort4*)&dh[off] = h;
  ushort4 l;
  l.x = f2bf(v.x - bf2f(h.x));
  l.y = f2bf(v.y - bf2f(h.y));
  l.z = f2bf(v.z - bf2f(h.z));
  l.w = f2bf(v.w - bf2f(h.w));
  *(ushort4*)&dl[off] = l;
}

// ========== z = x @ W_ih^T + (b_ih+b_hh) -> zbuf fp32 [B][4H] ===========
// 256 blocks = 2 m-tiles (64 rows) x 128 h-slices (32 gate cols each).
__global__ void __launch_bounds__(256)
z_split(const ushort* __restrict__ xh, const ushort* __restrict__ xl,
        const ushort* __restrict__ Wihh, const ushort* __restrict__ Wihl,
        const float* __restrict__ bih, const float* __restrict__ bhh,
        float* __restrict__ zbuf) {
  __shared__ alignas(16) ushort Ah[64][72];
  __shared__ alignas(16) ushort Al[64][72];
  __shared__ alignas(16) ushort Bh[32][72];
  __shared__ alignas(16) ushort Bl[32][72];
  const int tid = threadIdx.x, bid = blockIdx.x;
  const int m0 = (bid >> 7) * 64;
  const int hbase = (bid & 127) * 8;
  const int lane = tid & 63, wave = tid >> 6;
  const int wm = wave & 1, wn = wave >> 1;
  const int fr_row = lane & 15, fr_k = (lane >> 4) * 8;
  const f32x4 fz = {0.f, 0.f, 0.f, 0.f};

  f32x4 a0 = fz, a1 = fz;
  for (int kt = 0; kt < EE / 64; ++kt) {
    for (int i = 0; i < 2; ++i) {
      int idx = tid + i * 256;
      int r = idx >> 3, c8 = (idx & 7) * 8;
      int go = (m0 + r) * EE + kt * 64 + c8;
      *(uint4*)&Ah[r][c8] = *(const uint4*)&xh[go];
      *(uint4*)&Al[r][c8] = *(const uint4*)&xl[go];
    }
    {
      int r = tid >> 3, c8 = (tid & 7) * 8;
      int wrow = (r >> 3) * HH + hbase + (r & 7);
      int go = wrow * EE + kt * 64 + c8;
      *(uint4*)&Bh[r][c8] = *(const uint4*)&Wihh[go];
      *(uint4*)&Bl[r][c8] = *(const uint4*)&Wihl[go];
    }
    __syncthreads();
    for (int kc = 0; kc < 2; ++kc) {
      int ko = kc * 32 + fr_k;
      s16x8 bh = *(const s16x8*)&Bh[wn * 16 + fr_row][ko];
      s16x8 bl = *(const s16x8*)&Bl[wn * 16 + fr_row][ko];
      s16x8 f0h = *(const s16x8*)&Ah[wm * 32 + fr_row][ko];
      s16x8 f0l = *(const s16x8*)&Al[wm * 32 + fr_row][ko];
      s16x8 f1h = *(const s16x8*)&Ah[wm * 32 + 16 + fr_row][ko];
      s16x8 f1l = *(const s16x8*)&Al[wm * 32 + 16 + fr_row][ko];
      a0 = mfma_bf16(f0h, bh, a0);
      a0 = mfma_bf16(f0l, bh, a0);
      a0 = mfma_bf16(f0h, bl, a0);
      a1 = mfma_bf16(f1h, bh, a1);
      a1 = mfma_bf16(f1l, bh, a1);
      a1 = mfma_bf16(f1h, bl, a1);
    }
    __syncthreads();
  }
  int jcol = wn * 16 + fr_row;
  int gc = (jcol >> 3) * HH + hbase + (jcol & 7);
  float bias = bih[gc] + bhh[gc];
  int rbase = wm * 32 + (lane >> 4) * 4;
#pragma unroll
  for (int r = 0; r < 4; ++r) {
    zbuf[(size_t)(m0 + rbase + r) * G4 + gc] = a0[r] + bias;
    zbuf[(size_t)(m0 + rbase + 16 + r) * G4 + gc] = a1[r] + bias;
  }
}

// =====================================================================
// One step, kernel-boundary synced, FC fused one step delayed.
// Recurrence (t<T): 512 blocks = 4 m-tiles (32 rows) x 128 h-slices
//   (8 h cols; gate cols g*1024+hbase+c block-owned -> cell local).
//   512 blocks / 256 CUs = 2 blocks/CU -> co-resident blocks hide each
//   other's L2 staging latency (round-11 had 1/CU and was latency-bound).
// FC (t>0, bid<256): out[:, t-1, :] from h_{t-1}; 8 m-tiles x 32 o-tiles,
//   waves split K, LDS reduce. Reads only h_{t-1} -> no intra-step dep.
// =====================================================================
__global__ void __launch_bounds__(256)
step_kernel(const ushort* __restrict__ Whhh, const ushort* __restrict__ Whhl,
            const float* __restrict__ zbuf, float* __restrict__ cbuf,
            ushort* __restrict__ hbh, ushort* __restrict__ hbl,
            const ushort* __restrict__ fcwh, const ushort* __restrict__ fcwl,
            const float* __restrict__ fcb, float* __restrict__ out,
            float* __restrict__ out_ns, int t, int T) {
  __shared__ alignas(16) ushort Ah[32][72];
  __shared__ alignas(16) ushort Al[32][72];
  __shared__ alignas(16) ushort Bh[32][72];
  __shared__ alignas(16) ushort Bl[32][72];
  __shared__ alignas(16) float gs[32][32];
  __shared__ alignas(16) float fcred[4][16][16];

  const int tid = threadIdx.x;
  const int bid = blockIdx.x;
  const int m0 = (bid >> 7) * 32;     // 4 m-tiles of 32 rows
  const int hbase = (bid & 127) * 8;  // 128 h-slices
  const int lane = tid & 63;
  const int wave = tid >> 6;
  const int wm = wave & 1, wn = wave >> 1;
  const int fr_row = lane & 15, fr_k = (lane >> 4) * 8;
  const f32x4 fz = {0.f, 0.f, 0.f, 0.f};

  if (t < T) {
    f32x4 g0 = fz;
    if (t > 0) {
      const ushort* hph = hbh + ((t - 1) & 1) * (BB * HH);
      const ushort* hpl = hbl + ((t - 1) & 1) * (BB * HH);
      for (int kt = 0; kt < HH / 64; ++kt) {
        {
          int r = tid >> 3, c8 = (tid & 7) * 8;
          int go = (m0 + r) * HH + kt * 64 + c8;
          *(uint4*)&Ah[r][c8] = *(const uint4*)&hph[go];
          *(uint4*)&Al[r][c8] = *(const uint4*)&hpl[go];
          int wrow = (r >> 3) * HH + hbase + (r & 7);
          int gw = wrow * HH + kt * 64 + c8;
          *(uint4*)&Bh[r][c8] = *(const uint4*)&Whhh[gw];
          *(uint4*)&Bl[r][c8] = *(const uint4*)&Whhl[gw];
        }
        __syncthreads();
        for (int kc = 0; kc < 2; ++kc) {
          int ko = kc * 32 + fr_k;
          s16x8 bh = *(const s16x8*)&Bh[wn * 16 + fr_row][ko];
          s16x8 bl = *(const s16x8*)&Bl[wn * 16 + fr_row][ko];
          s16x8 fh = *(const s16x8*)&Ah[wm * 16 + fr_row][ko];
          s16x8 fl = *(const s16x8*)&Al[wm * 16 + fr_row][ko];
          g0 = mfma_bf16(fh, bh, g0);
          g0 = mfma_bf16(fl, bh, g0);
          g0 = mfma_bf16(fh, bl, g0);
        }
        __syncthreads();
      }
    }
    // scatter gate accumulator to LDS
    {
      int jcol = wn * 16 + fr_row;
      int rbase = wm * 16 + (lane >> 4) * 4;
#pragma unroll
      for (int r = 0; r < 4; ++r) gs[rbase + r][jcol] = g0[r];
    }
    __syncthreads();
    // elementwise LSTM cell (fp32); h stored split bf16, c fp32 global
    {
      int m = tid >> 3, c = tid & 7;  // 32 rows x 8 cols, 1 elem/thread
      int gb = m0 + m;
      int hc = hbase + c;
      const float* zb = zbuf + (size_t)gb * G4;
      float cv = (t == 0) ? 0.f : cbuf[gb * HH + hc];
      float iv = sigm(zb[hc] + gs[m][c]);
      float fv = sigm(zb[HH + hc] + gs[m][8 + c]);
      float gv = tanhf(zb[2 * HH + hc] + gs[m][16 + c]);
      float ov = sigm(zb[3 * HH + hc] + gs[m][24 + c]);
      float cc = fv * cv + iv * gv;
      cbuf[gb * HH + hc] = cc;
      float hv = ov * tanhf(cc);
      ushort hh = f2bf(hv);
      ushort hl = f2bf(hv - bf2f(hh));
      size_t go = (size_t)(t & 1) * (BB * HH) + gb * HH + hc;
      hbh[go] = hh;
      hbl[go] = hl;
      if (t == T - 1 && gb == BB - 1) out_ns[hc] = hv;
    }
  }

  // ------------- delayed FC: out[:, t-1, :] from h_{t-1} ----------------
  if (t > 0 && bid < 256) {
    const int m0f = (bid >> 5) * 16;
    const int o0 = (bid & 31) * 16;
    const ushort* hch = hbh + ((t - 1) & 1) * (BB * HH);
    const ushort* hcl = hbl + ((t - 1) & 1) * (BB * HH);
    f32x4 acc = fz;
    const int kbase = wave * 256;
    for (int k8 = 0; k8 < 8; ++k8) {
      int kk = kbase + k8 * 32 + fr_k;
      s16x8 afh = *(const s16x8*)&hch[(m0f + fr_row) * HH + kk];
      s16x8 afl = *(const s16x8*)&hcl[(m0f + fr_row) * HH + kk];
      s16x8 bh = *(const s16x8*)&fcwh[(o0 + fr_row) * HH + kk];
      s16x8 bl = *(const s16x8*)&fcwl[(o0 + fr_row) * HH + kk];
      acc = mfma_bf16(afh, bh, acc);
      acc = mfma_bf16(afl, bh, acc);
      acc = mfma_bf16(afh, bl, acc);
    }
    int rrow = (lane >> 4) * 4;
#pragma unroll
    for (int r = 0; r < 4; ++r) fcred[wave][rrow + r][fr_row] = acc[r];
    __syncthreads();
    {
      int row = tid >> 4, col = tid & 15;
      float s = fcred[0][row][col] + fcred[1][row][col] + fcred[2][row][col] +
                fcred[3][row][col] + fcb[o0 + col];
      out[((size_t)(m0f + row) * T + (t - 1)) * OO + o0 + col] = s;
    }
  }
}

extern "C" void kernel_launch(void* const* d_in, const int* in_sizes, int n_in,
                              void* d_out, int out_size, void* d_ws,
                              size_t ws_size, hipStream_t stream) {
  (void)ws_size;
  // ---- order-agnostic input identification by element count ----
  const float *x = nullptr, *Wih = nullptr, *Whh = nullptr, *fcw = nullptr;
  const float *bih = nullptr, *bhh = nullptr, *fcb = nullptr;
  for (int i = 0; i < n_in; ++i) {
    int s = in_sizes[i];
    const float* p = (const float*)d_in[i];
    if (s == BB * EE && !x) x = p;
    else if (s == G4 * EE && !Wih) Wih = p;
    else if (s == G4 * HH && !Whh) Whh = p;
    else if (s == OO * HH && !fcw) fcw = p;
    else if (s == G4 && !bih) bih = p;
    else if (s == G4 && !bhh) bhh = p;  // bias order irrelevant (summed)
    else if (s == OO && !fcb) fcb = p;
  }
  if (!x || !Wih || !Whh || !fcw || !bih || !bhh || !fcb) return;

  // ---- runtime T from out_size ----
  int T = 0;
  if (out_size >= BB * OO && (out_size - HH) % (BB * OO) == 0 &&
      (out_size - HH) / (BB * OO) >= 1) {
    T = (out_size - HH) / (BB * OO);
  } else if (out_size % (BB * OO) == 0) {
    T = out_size / (BB * OO);
  }
  if (T < 1 || T > 16384) return;

  float* out = (float*)d_out;
  float* out_ns = out + (size_t)BB * T * OO;

  // ---- ws layout ----
  ushort* xh = (ushort*)d_ws;
  ushort* xl = xh + (size_t)BB * EE;
  ushort* Wihh = xl + (size_t)BB * EE;
  ushort* Wihl = Wihh + (size_t)G4 * EE;
  ushort* Whhh = Wihl + (size_t)G4 * EE;
  ushort* Whhl = Whhh + (size_t)G4 * HH;
  ushort* fcwh = Whhl + (size_t)G4 * HH;
  ushort* fcwl = fcwh + (size_t)OO * HH;
  ushort* hbh = fcwl + (size_t)OO * HH;
  ushort* hbl = hbh + (size_t)2 * BB * HH;
  float* zbuf = (float*)(hbl + (size_t)2 * BB * HH);  // 128*4096 f32
  float* cbuf = zbuf + (size_t)BB * G4;               // 128*1024 f32

  {
    long total = (long)BB * EE + (long)G4 * EE + (long)G4 * HH + (long)OO * HH;
    int cblocks = (int)(total / 4 / 256);  // exact
    hipLaunchKernelGGL(convert_split, dim3(cblocks), dim3(256), 0, stream, x,
                       Wih, Whh, fcw, xh, xl, Wihh, Wihl, Whhh, Whhl, fcwh,
                       fcwl);
  }
  hipLaunchKernelGGL(z_split, dim3(256), dim3(256), 0, stream, xh, xl, Wihh,
                     Wihl, bih, bhh, zbuf);

  for (int t = 0; t <= T; ++t) {
    hipLaunchKernelGGL(step_kernel, dim3(512), dim3(256), 0, stream, Whhh,
                       Whhl, zbuf, cbuf, hbh, hbl, fcwh, fcwl, fcb, out,
                       out_ns, t, T);
  }
}